// Round 8
// baseline (85.199 us; speedup 1.0000x reference)
//
#include <hip/hip_runtime.h>
#include <hip/hip_fp16.h>

#define DEG 32
#define K_KNOTS 7
#define NINT 6  // K-1 intervals

typedef _Float16 half_t;
typedef _Float16 h2 __attribute__((ext_vector_type(2)));

// 8-byte packed edge record: unit vector (fp16 x3) + f-spline value (fp16),
// stored as two half2: (x,y) and (z,f). 320k edges * 8 B = 2.56 MB + su 640 KB
// keeps the phase-2 random gather L2-resident (fits each XCD's 4 MB L2).
union UF8 {
    uint2 u;
    struct { h2 xy; h2 zf; } h;
};

__device__ inline float fdot2(h2 a, h2 b, float c) {
#if __has_builtin(__builtin_amdgcn_fdot2)
    return __builtin_amdgcn_fdot2(a, b, c, false);
#else
    return (float)a.x * (float)b.x + (float)a.y * (float)b.y + c;
#endif
}

// Natural cubic spline, uniform knot spacing h. y[7] -> C[6].
// Coefficients RESCALED to the unit interval (b*h, c*h^2, d*h^3):
// value = C.x + t*(C.y + t*(C.z + t*C.w)), t = u - idx, u = (x - t0)/h.
__device__ inline void spline_coeffs(const float* __restrict__ y, float h, float4* C) {
    float dy[NINT];
#pragma unroll
    for (int i = 0; i < NINT; ++i) dy[i] = (y[i + 1] - y[i]) / h;
    float rhs[5];
#pragma unroll
    for (int i = 0; i < 5; ++i) rhs[i] = 6.0f * (dy[i + 1] - dy[i]);
    // Thomas algorithm, n=5, diag=4h, off=h
    float cp[5], dp[5];
    float denom = 4.0f * h;
    cp[0] = h / denom;
    dp[0] = rhs[0] / denom;
#pragma unroll
    for (int i = 1; i < 5; ++i) {
        denom = 4.0f * h - h * cp[i - 1];
        cp[i] = h / denom;
        dp[i] = (rhs[i] - h * dp[i - 1]) / denom;
    }
    float M[K_KNOTS];
    M[0] = 0.0f; M[6] = 0.0f;
    M[5] = dp[4];
#pragma unroll
    for (int i = 3; i >= 0; --i) M[i + 1] = dp[i] - cp[i] * M[i + 2];
#pragma unroll
    for (int i = 0; i < NINT; ++i) {
        float b = dy[i] - h * (2.0f * M[i] + M[i + 1]) * (1.0f / 6.0f);
        float c = M[i] * 0.5f;
        float d = (M[i + 1] - M[i]) / (6.0f * h);
        C[i].x = y[i];
        C[i].y = b * h;
        C[i].z = c * h * h;
        C[i].w = d * h * h * h;
    }
}

// Phase 1: per-edge. l = |r_e|, u_e = r_e/l, f_e = f(l); pack to 8 B.
// Also emits su[e] = (ushort)src[e] (src < 10000 fits 14 bits).
__global__ __launch_bounds__(256) void edge_kernel(
    const float* __restrict__ r, const float* __restrict__ fc,
    const int* __restrict__ src,
    uint2* __restrict__ uf, unsigned short* __restrict__ su, int E) {
    __shared__ float4 sF[NINT];
    if (threadIdx.x == 0) {
        float4 c[NINT];
        spline_coeffs(fc, 8.0f / 6.0f, c);  // radial knots linspace(0,8,7)
#pragma unroll
        for (int i = 0; i < NINT; ++i) sF[i] = c[i];
    }
    __syncthreads();
    int e = blockIdx.x * blockDim.x + threadIdx.x;
    if (e >= E) return;
    float x = r[3 * e + 0];
    float y = r[3 * e + 1];
    float z = r[3 * e + 2];
    float d = x * x + y * y + z * z;
    float rl = rsqrtf(d);
    float l = d * rl;          // |r|
    // f(l): u = l/h >= 0 so trunc == floor; idx clamp extrapolates (l > 8)
    float u = l * (6.0f / 8.0f);
    int idx = (int)u;
    idx = idx > NINT - 1 ? NINT - 1 : idx;
    float t = u - (float)idx;
    float4 c = sF[idx];
    float f = c.x + t * (c.y + t * (c.z + t * c.w));
    UF8 q;
    q.h.xy.x = (half_t)(x * rl);
    q.h.xy.y = (half_t)(y * rl);
    q.h.zf.x = (half_t)(z * rl);
    q.h.zf.y = (half_t)f;
    uf[e] = q.u;
    su[e] = (unsigned short)src[e];
}

// Phase 2, R10: EIGHT lanes per edge (was 4 in R7/R9). Total scattered
// line-visits per wave are unchanged (64), but wave count doubles (more TLP
// at the 8-waves/SIMD cap to hide the ~200-cyc L2 gather latency), the
// per-lane serial chain halves (4 triplets), and VGPR use drops (rq[2]).
// Tests the latency-bound hypothesis left by R9's null (VALU/byte thinning
// moved nothing). Lane p of edge e owns records [4p, 4p+4): 2 x uint4 from
// the uf block + 1 x uint2 from the su block; 3-round shfl_xor reduces the
// 8-lane group. dst[e] = e>>5 by construction.
__global__ __launch_bounds__(256) void triplet_kernel(
    const uint2* __restrict__ uf, const float* __restrict__ gc,
    const unsigned short* __restrict__ su,
    float* __restrict__ out, int E) {
    __shared__ float4 sG[NINT];
    if (threadIdx.x == 0) {
        float4 c[NINT];
        spline_coeffs(gc, 2.0f / 6.0f, c);  // angular knots linspace(-1,1,7)
#pragma unroll
        for (int i = 0; i < NINT; ++i) sG[i] = c[i];
    }
    __syncthreads();

    int t = blockIdx.x * blockDim.x + threadIdx.x;
    int e = t >> 3;          // 8 consecutive lanes share one edge
    int p = t & 7;           // lane's slice of the neighbor block
    if (e >= E) return;

    int a = (int)su[e];      // src[e]; same addr for the 8 group lanes
    unsigned de2 = ((unsigned)(e >> 5)) * 0x00010001u;  // dst[e] packed x2
    UF8 qe; qe.u = uf[e];
    // negated e-side unit vector, once: cos = dot(u_k, -u_e)
    uint2 neg = qe.u;
    neg.x ^= 0x80008000u;    // -(x,y)
    neg.y ^= 0x00008000u;    // -(z), keep f
    h2 ne_xy = __builtin_bit_cast(h2, neg.x);
    h2 ne_zf = __builtin_bit_cast(h2, neg.y);
    h2 ne_z0; ne_z0.x = ne_zf.x; ne_z0.y = (half_t)0.0f;
    float fe = (float)qe.h.zf.y;

    // lane's 4 records: blk[2p], blk[2p+1] (32 B) + uint2 of 4 ushort ids.
    const uint4* blk = (const uint4*)(uf + (size_t)a * DEG);
    uint4 rq[2];
    rq[0] = blk[2 * p];
    rq[1] = blk[2 * p + 1];
    uint2 sq = ((const uint2*)(su + (size_t)a * DEG))[p];

    float acc = 0.0f;
#pragma unroll
    for (int rr = 0; rr < 4; ++rr) {
        uint4 qq = rq[rr >> 1];
        unsigned w0 = (rr & 1) ? qq.z : qq.x;
        unsigned w1 = (rr & 1) ? qq.w : qq.y;
        // packed src-id pair for records {2k, 2k+1}, k = rr>>1
        unsigned sw = (rr >> 1) == 0 ? sq.x : sq.y;
        unsigned v = sw ^ de2;
        bool keep = (rr & 1) ? (v >> 16) != 0u : (v & 0xFFFFu) != 0u;
        h2 kxy = __builtin_bit_cast(h2, w0);
        h2 kzf = __builtin_bit_cast(h2, w1);
        float cosv = fdot2(kxy, ne_xy, fdot2(kzf, ne_z0, 0.0f));
        // g(cos): u = (cos+1)*3 in [-6e-3, 6+6e-3]; trunc(-eps)=0 and the
        // idx clamp handle both ends (tiny bounded extrapolation, no clamp)
        float u = __builtin_fmaf(cosv, 3.0f, 3.0f);
        int idx = (int)u;
        idx = idx > NINT - 1 ? NINT - 1 : idx;
        float tt = u - (float)idx;
        float4 c = sG[idx];
        float g = c.x + tt * (c.y + tt * (c.z + tt * c.w));
        float fk = (float)kzf.y;
        acc += keep ? fk * g : 0.0f;
    }

    // reduce the 8-lane group (xor 1,2,4 stay within the group)
    acc += __shfl_xor(acc, 1, 64);
    acc += __shfl_xor(acc, 2, 64);
    acc += __shfl_xor(acc, 4, 64);
    if (p == 0) out[e] = fe * acc;
}

extern "C" void kernel_launch(void* const* d_in, const int* in_sizes, int n_in,
                              void* d_out, int out_size, void* d_ws, size_t ws_size,
                              hipStream_t stream) {
    const float* r   = (const float*)d_in[0];
    const float* fc  = (const float*)d_in[1];
    const float* gc  = (const float*)d_in[2];
    const int* src   = (const int*)d_in[3];
    float* out = (float*)d_out;
    int E = in_sizes[3];

    // ws layout: uf (E*8 B) | su (E*2 B)
    uint2* uf = (uint2*)d_ws;
    unsigned short* su = (unsigned short*)((char*)d_ws + (size_t)E * 8);

    int threads = 256;
    int blocks1 = (E + threads - 1) / threads;
    edge_kernel<<<blocks1, threads, 0, stream>>>(r, fc, src, uf, su, E);

    long long T2 = (long long)E * 8;   // 8 lanes per edge
    int blocks2 = (int)((T2 + threads - 1) / threads);
    triplet_kernel<<<blocks2, threads, 0, stream>>>(uf, gc, su, out, E);
}

// Round 9
// 80.968 us; speedup vs baseline: 1.0523x; 1.0523x over previous
//
#include <hip/hip_runtime.h>
#include <hip/hip_fp16.h>

#define DEG 32
#define K_KNOTS 7
#define NINT 6  // K-1 intervals

typedef _Float16 half_t;
typedef _Float16 h2 __attribute__((ext_vector_type(2)));

// 8-byte packed edge record: unit vector (fp16 x3) + f-spline value (fp16),
// stored as two half2: (x,y) and (z,f). 320k edges * 8 B = 2.56 MB keeps the
// phase-2 random gather L2-resident.
union UF8 {
    uint2 u;
    struct { h2 xy; h2 zf; } h;
};

__device__ inline float fdot2(h2 a, h2 b, float c) {
#if __has_builtin(__builtin_amdgcn_fdot2)
    return __builtin_amdgcn_fdot2(a, b, c, false);
#else
    return (float)a.x * (float)b.x + (float)a.y * (float)b.y + c;
#endif
}

// Natural cubic spline with uniform knot spacing h. y[7] -> C[6] = (a,b,c,d).
// Mirrors reference: tridiag(main=4h, off=h) solve for interior 2nd derivs.
__device__ inline void spline_coeffs(const float* __restrict__ y, float h, float4* C) {
    float dy[NINT];
#pragma unroll
    for (int i = 0; i < NINT; ++i) dy[i] = (y[i + 1] - y[i]) / h;
    float rhs[5];
#pragma unroll
    for (int i = 0; i < 5; ++i) rhs[i] = 6.0f * (dy[i + 1] - dy[i]);
    // Thomas algorithm, n=5, diag=4h, off=h
    float cp[5], dp[5];
    float denom = 4.0f * h;
    cp[0] = h / denom;
    dp[0] = rhs[0] / denom;
#pragma unroll
    for (int i = 1; i < 5; ++i) {
        denom = 4.0f * h - h * cp[i - 1];
        cp[i] = h / denom;
        dp[i] = (rhs[i] - h * dp[i - 1]) / denom;
    }
    float M[K_KNOTS];
    M[0] = 0.0f; M[6] = 0.0f;
    M[5] = dp[4];
#pragma unroll
    for (int i = 3; i >= 0; --i) M[i + 1] = dp[i] - cp[i] * M[i + 2];
#pragma unroll
    for (int i = 0; i < NINT; ++i) {
        C[i].x = y[i];
        C[i].y = dy[i] - h * (2.0f * M[i] + M[i + 1]) * (1.0f / 6.0f);
        C[i].z = M[i] * 0.5f;
        C[i].w = (M[i + 1] - M[i]) / (6.0f * h);
    }
}

// Phase 1: per-edge. l = |r_e|, u_e = r_e/l, f_e = f(l); pack to 8 B.
__global__ __launch_bounds__(256) void edge_kernel(
    const float* __restrict__ r, const float* __restrict__ fc,
    uint2* __restrict__ uf, int E) {
    __shared__ float4 sF[NINT];
    if (threadIdx.x == 0) {
        float4 c[NINT];
        spline_coeffs(fc, 8.0f / 6.0f, c);  // radial knots linspace(0,8,7)
#pragma unroll
        for (int i = 0; i < NINT; ++i) sF[i] = c[i];
    }
    __syncthreads();
    int e = blockIdx.x * blockDim.x + threadIdx.x;
    if (e >= E) return;
    float x = r[3 * e + 0];
    float y = r[3 * e + 1];
    float z = r[3 * e + 2];
    float d = x * x + y * y + z * z;
    float rl = rsqrtf(d);
    float l = d * rl;          // |r|
    // f(l): l >= 0 so trunc == floor; idx clamp handles extrapolation (l > 8)
    float u = l * (6.0f / 8.0f);
    int idx = (int)u;
    idx = idx < 0 ? 0 : (idx > NINT - 1 ? NINT - 1 : idx);
    float s = l - (8.0f / 6.0f) * (float)idx;
    float4 c = sF[idx];
    float f = c.x + s * (c.y + s * (c.z + s * c.w));
    UF8 q;
    q.h.xy.x = (half_t)(x * rl);
    q.h.xy.y = (half_t)(y * rl);
    q.h.zf.x = (half_t)(z * rl);
    q.h.zf.y = (half_t)f;
    uf[e] = q.u;
}

// Phase 2: FOUR lanes per edge — the verified optimum of this session's
// structure space (1 lane/edge: 64-scattered-line loads; 8 lanes/edge R10:
// +3.5 us from doubled per-edge fixed work; node-centric R5/R6: +27..44 us;
// fusion R8: +5 us; thinning R9: null). Lane group q=0..3 of edge e loads
// 64 B of the 256 B neighbor block -> per unroll slot the 4 lanes cover one
// contiguous cache line; each lane accumulates its 8 triplets; 2-round shfl
// reduces the group. dst[e] = e>>5 by construction.
__global__ __launch_bounds__(256) void triplet_kernel(
    const uint2* __restrict__ uf, const float* __restrict__ gc,
    const int* __restrict__ src,
    float* __restrict__ out, int E) {
    __shared__ float4 sG[NINT];
    if (threadIdx.x == 0) {
        float4 c[NINT];
        spline_coeffs(gc, 2.0f / 6.0f, c);  // angular knots linspace(-1,1,7)
#pragma unroll
        for (int i = 0; i < NINT; ++i) sG[i] = c[i];
    }
    __syncthreads();

    int t = blockIdx.x * blockDim.x + threadIdx.x;
    int e = t >> 2;          // 4 consecutive lanes share one edge
    int q = t & 3;           // lane's slice of the neighbor block
    if (e >= E) return;

    int a = src[e];          // same addr for the 4 group lanes
    int de = e >> 5;         // dst[e] = e / DEG by construction
    UF8 qe; qe.u = uf[e];
    // negated e-side unit vector, once: cos = dot(u_k, -u_e)
    uint2 neg = qe.u;
    neg.x ^= 0x80008000u;    // -(x,y)
    neg.y ^= 0x00008000u;    // -(z), keep f
    h2 ne_xy = __builtin_bit_cast(h2, neg.x);
    h2 ne_zf = __builtin_bit_cast(h2, neg.y);
    h2 ne_z0; ne_z0.x = ne_zf.x; ne_z0.y = (half_t)0.0f;
    float fe = (float)qe.h.zf.y;

    // lane's 8 records: uint4 slot it covers records q*8+2it, q*8+2it+1;
    // 4 lanes at slot it = contiguous 64 B.
    const uint4* blk = (const uint4*)(uf + (size_t)a * DEG);
    const int4* sblk = (const int4*)(src + (size_t)a * DEG);
    uint4 rq[4];
    int4 sq[2];
#pragma unroll
    for (int it = 0; it < 4; ++it) rq[it] = blk[q * 4 + it];
#pragma unroll
    for (int it = 0; it < 2; ++it) sq[it] = sblk[q * 2 + it];

    float acc = 0.0f;
#pragma unroll
    for (int rr = 0; rr < 8; ++rr) {
        uint4 qq = rq[rr >> 1];
        unsigned w0 = (rr & 1) ? qq.z : qq.x;
        unsigned w1 = (rr & 1) ? qq.w : qq.y;
        int4 sv = sq[rr >> 2];
        int s2 = (rr & 3) == 0 ? sv.x : (rr & 3) == 1 ? sv.y
               : (rr & 3) == 2 ? sv.z : sv.w;
        h2 kxy = __builtin_bit_cast(h2, w0);
        h2 kzf = __builtin_bit_cast(h2, w1);
        float cosv = fdot2(kxy, ne_xy, fdot2(kzf, ne_z0, 0.0f));
        cosv = fminf(fmaxf(cosv, -1.0f), 1.0f);
        // g(cos): cos in [-1,1] -> u in [0,6]; trunc == floor (u >= 0)
        float u = (cosv + 1.0f) * 3.0f;
        int idx = (int)u;
        idx = idx > NINT - 1 ? NINT - 1 : idx;
        float s = cosv - (-1.0f + (2.0f / 6.0f) * (float)idx);
        float4 c = sG[idx];
        float g = c.x + s * (c.y + s * (c.z + s * c.w));
        float fk = (float)kzf.y;
        float term = (s2 != de) ? fk * g : 0.0f;
        acc += term;
    }

    // reduce the 4-lane group (xor 1,2 stay within the group)
    acc += __shfl_xor(acc, 1, 64);
    acc += __shfl_xor(acc, 2, 64);
    if (q == 0) out[e] = fe * acc;
}

extern "C" void kernel_launch(void* const* d_in, const int* in_sizes, int n_in,
                              void* d_out, int out_size, void* d_ws, size_t ws_size,
                              hipStream_t stream) {
    const float* r   = (const float*)d_in[0];
    const float* fc  = (const float*)d_in[1];
    const float* gc  = (const float*)d_in[2];
    const int* src   = (const int*)d_in[3];
    float* out = (float*)d_out;
    int E = in_sizes[3];

    uint2* uf = (uint2*)d_ws;  // E * 8 bytes

    int threads = 256;
    int blocks1 = (E + threads - 1) / threads;
    edge_kernel<<<blocks1, threads, 0, stream>>>(r, fc, uf, E);

    long long T2 = (long long)E * 4;   // 4 lanes per edge
    int blocks2 = (int)((T2 + threads - 1) / threads);
    triplet_kernel<<<blocks2, threads, 0, stream>>>(uf, gc, src, out, E);
}